// Round 7
// baseline (670.440 us; speedup 1.0000x reference)
//
#include <hip/hip_runtime.h>
#include <hip/hip_bf16.h>
#include <cstddef>
#include <climits>

// Problem constants
#define BB   16
#define LL   2048
#define DD   1024
#define SS   64
#define HH   512
#define H3   1536
#define NCLS 3
#define GPB  16   // WGs per batch per GRU role (each owns 32 of 512 hidden dims)

typedef _Float16 half2_t __attribute__((ext_vector_type(2)));
typedef _Float16 f16x8  __attribute__((ext_vector_type(8)));
typedef float    f32x4  __attribute__((ext_vector_type(4)));

static __device__ __forceinline__ half2_t u2h2(unsigned int u) {
    union { unsigned int u; half2_t h; } cv; cv.u = u; return cv.h;
}
static __device__ __forceinline__ unsigned short f2h(float f) {
    _Float16 h = (_Float16)f;
    union { _Float16 h; unsigned short u; } cv; cv.h = h; return cv.u;
}

// ---------------------------------------------------------------------------
// 1) Mega-prep kernel: pooling + 3 weight packs + 3 f16 converts + flag zero.
//    Block ranges:
//      [0,1024)            pooling, r = blk (s*16+b)
//      [1024,1024+2304)    pack {W_hh0,W_hh1,W_ih1} -> k-major f16-pair dwords
//      [3328,3328+896)     cvt  {W_down,W_ih0,W_lin1} -> f16
//      [4224]              zero ALL 768 sync flags (grid-stride: R6 bug was
//                          `if (tid<768)` with 256 threads -> flag_ih/flag1
//                          stayed 0xAA-poisoned (negative) -> role-2 deadlock)
// ---------------------------------------------------------------------------
__global__ __launch_bounds__(256) void prep_pool_kernel(
        const float* __restrict__ hs, const int* __restrict__ gidx,
        float* __restrict__ pooled, _Float16* __restrict__ pooledh,
        const float* __restrict__ W_hh0, const float* __restrict__ W_hh1,
        const float* __restrict__ W_ih1,
        unsigned int* __restrict__ wp0, unsigned int* __restrict__ wp1,
        unsigned int* __restrict__ wpih1,
        const float* __restrict__ W_down, const float* __restrict__ W_ih0,
        const float* __restrict__ W_lin1,
        _Float16* __restrict__ wdown_h, _Float16* __restrict__ wih0_h,
        _Float16* __restrict__ wlin1_h,
        int* __restrict__ flags)          // 768 ints
{
    __shared__ int   lst[LL];
    __shared__ int   cnt;
    __shared__ float tpk[32][33];
    const int blk = blockIdx.x;
    const int tid = threadIdx.x;

    if (blk < 1024) {
        // ---- segment-mean pooling; output (S,B,D) row r = s*16+b ----
        const int r = blk;
        const int b = r & 15;
        const int s = r >> 4;
        if (tid == 0) cnt = 0;
        __syncthreads();
        const int* gi = gidx + b * LL;
        for (int l = tid; l < LL; l += 256) {
            if (gi[l] == s) { int p = atomicAdd(&cnt, 1); lst[p] = l; }
        }
        __syncthreads();
        const int c = cnt;
        const float* hb = hs + (size_t)b * LL * DD;
        const int d0 = tid * 4;
        float4 acc = make_float4(0.f, 0.f, 0.f, 0.f);
        for (int i = 0; i < c; ++i) {
            const float4 v = *(const float4*)(hb + (size_t)lst[i] * DD + d0);
            acc.x += v.x; acc.y += v.y; acc.z += v.z; acc.w += v.w;
        }
        const float inv = 1.0f / (float)c;
        float4 o = make_float4(acc.x * inv, acc.y * inv, acc.z * inv, acc.w * inv);
        *(float4*)(pooled + (size_t)r * DD + d0) = o;
        ushort4 oh;
        oh.x = f2h(o.x); oh.y = f2h(o.y); oh.z = f2h(o.z); oh.w = f2h(o.w);
        *(ushort4*)(pooledh + (size_t)r * DD + d0) = oh;
        return;
    }
    int t = blk - 1024;
    if (t < 2304) {
        // ---- transpose + f16-pack a (1536x512) matrix into (256x1536) ----
        const float* W; unsigned int* Wp;
        if (t < 768)       { W = W_hh0; Wp = wp0; }
        else if (t < 1536) { W = W_hh1; Wp = wp1;   t -= 768; }
        else               { W = W_ih1; Wp = wpih1; t -= 1536; }
        const int k0 = (t & 15) * 32;
        const int g0 = (t >> 4) * 32;
        const int tx = tid & 31;
        const int ty = tid >> 5;        // 0..7
        for (int i = ty; i < 32; i += 8)
            tpk[i][tx] = W[(size_t)(g0 + i) * HH + k0 + tx];
        __syncthreads();
        for (int i = ty; i < 16; i += 8) {
            const float lo = tpk[tx][2 * i];
            const float hi = tpk[tx][2 * i + 1];
            const unsigned int p = (unsigned int)f2h(lo) | ((unsigned int)f2h(hi) << 16);
            Wp[(size_t)(k0 / 2 + i) * H3 + g0 + tx] = p;
        }
        return;
    }
    t -= 2304;
    if (t < 896) {
        // ---- fp32 -> f16 convert ----
        const float* src; _Float16* dst;
        if (t < 256)      { src = W_down; dst = wdown_h; }
        else if (t < 640) { src = W_ih0;  dst = wih0_h;  t -= 256; }
        else              { src = W_lin1; dst = wlin1_h; t -= 640; }
        const int i = (t * 256 + tid) * 8;
        const float4 a = *(const float4*)(src + i);
        const float4 b = *(const float4*)(src + i + 4);
        ushort4 u0, u1;
        u0.x = f2h(a.x); u0.y = f2h(a.y); u0.z = f2h(a.z); u0.w = f2h(a.w);
        u1.x = f2h(b.x); u1.y = f2h(b.y); u1.z = f2h(b.z); u1.w = f2h(b.w);
        *(ushort4*)(dst + i)     = u0;
        *(ushort4*)(dst + i + 4) = u1;
        return;
    }
    // ---- zero ALL sync flags (grid-stride; blockDim is 256, flags are 768)
    for (int i = tid; i < 768; i += 256) flags[i] = 0;
}

// ---------------------------------------------------------------------------
// 2) f16 MFMA GEMM (compile-time K): C[M,N] = A[M,K] @ W[N,K]^T + bias
//    (+resid for fp32 out). 64x64 tile per WG, 4 waves, verified fragment
//    mappings (m89/m97). Full k-unroll lets the compiler hoist loads.
// ---------------------------------------------------------------------------
template <int K, bool F16OUT>
__global__ __launch_bounds__(256) void gemm_mfma_kernel(
        const _Float16* __restrict__ A,
        const _Float16* __restrict__ W,
        const float*    __restrict__ bias,
        const float*    __restrict__ resid,   // nullable, fp32-out only
        void*           __restrict__ C,
        int N)
{
    const int tid  = threadIdx.x;
    const int wv   = tid >> 6;
    const int lane = tid & 63;
    const int m0 = blockIdx.y * 64 + wv * 16;
    const int n0 = blockIdx.x * 64;
    const int l15 = lane & 15;
    const int ko  = (lane >> 4) * 8;

    const _Float16* Ap = A + (size_t)(m0 + l15) * K + ko;
    const _Float16* Wp = W + (size_t)(n0 + l15) * K + ko;

    f32x4 acc[4] = {};
#pragma unroll
    for (int k0 = 0; k0 < K; k0 += 32) {
        const f16x8 a = *(const f16x8*)(Ap + k0);
#pragma unroll
        for (int nb = 0; nb < 4; ++nb) {
            const f16x8 bq = *(const f16x8*)(Wp + (size_t)nb * 16 * K + k0);
            acc[nb] = __builtin_amdgcn_mfma_f32_16x16x32_f16(a, bq, acc[nb], 0, 0, 0);
        }
    }
    const int crow = m0 + (lane >> 4) * 4;
#pragma unroll
    for (int nb = 0; nb < 4; ++nb) {
        const int col = n0 + nb * 16 + l15;
        const float bb = bias[col];
#pragma unroll
        for (int rg = 0; rg < 4; ++rg) {
            float v = acc[nb][rg] + bb;
            const size_t off = (size_t)(crow + rg) * N + col;
            if (F16OUT) {
                ((_Float16*)C)[off] = (_Float16)v;
            } else {
                if (resid) v += resid[off];
                ((float*)C)[off] = v;
            }
        }
    }
}

// ---------------------------------------------------------------------------
// 3) Fused two-layer pipelined GRU. 768 WGs, 3 roles (WG-uniform):
//      role 0 (blk 0..255):   layer-0 recurrence (WG (b,p): dims 32p..32p+32)
//      role 1 (blk 256..511): layer-1 input projection xW1[t] = ys0[t]@W_ih1^T
//                             (WG (b,q) produces exactly the 96 cols that
//                              hh-WG (b,q) consumes -> point-to-point flag)
//      role 2 (blk 512..767): layer-1 recurrence
//    Dependency graph L0 -> ih -> hh is acyclic => deadlock-free under any
//    scheduling (even 1 block/CU residency: roles drain in order).
//    Exchange buffers are 64-deep (write-once, no WAR hazard). All cross-WG
//    data moves via RELAXED agent-scope (sc1, cache-bypassing) atomics;
//    every flag store is wave-0, after s_waitcnt vmcnt(0) in the same wave
//    covering all payload stores (R4-verified pattern).
// ---------------------------------------------------------------------------
__global__ __launch_bounds__(256) void gru_fused_kernel(
        const _Float16*     __restrict__ xW0,    // (S*B,1536) f16, row=t*16+b
        const unsigned int* __restrict__ wp_hh0, // (256,1536) f16-pair dwords
        const float*        __restrict__ b_hh0,
        const unsigned int* __restrict__ wp_ih1,
        const float*        __restrict__ b_ih1,
        const unsigned int* __restrict__ wp_hh1,
        const float*        __restrict__ b_hh1,
        _Float16*           __restrict__ ys1,    // (S*B,512) f16
        unsigned int*       __restrict__ hbuf0,  // (S*B,256) f16-pair dwords
        unsigned int*       __restrict__ hbuf1,  // (S*B,256)
        unsigned int*       __restrict__ xw1buf, // (S*B,16,48) f16-pair dwords
        int*                __restrict__ flag0,  // (B,16) pre-zeroed
        int*                __restrict__ flag_ih,// (B,16)
        int*                __restrict__ flag1)  // (B,16)
{
    __shared__ __align__(16) unsigned int hls[256];
    __shared__ float dots[96];

    const int blk  = blockIdx.x;
    const int role = blk >> 8;                 // 0,1,2
    const int sub  = blk & 255;
    const int b    = sub & 15;
    const int p    = sub >> 4;
    const int tid  = threadIdx.x;

    // dot-thread assignment: tid = 2*r + half, r = gate*32 + jl (tid<192)
    const int r    = tid >> 1;
    const int half = tid & 1;
    const int gate = r >> 5;
    const int jl   = r & 31;
    const int col  = gate * HH + p * 32 + jl;

    const unsigned int* wsrc = (role == 0) ? wp_hh0 : (role == 1 ? wp_ih1 : wp_hh1);
    const float*        bsrc = (role == 0) ? b_hh0  : (role == 1 ? b_ih1  : b_hh1);

    float bias = 0.f;
    unsigned int wreg[128];
    if (tid < 192) {
        bias = bsrc[col];
#pragma unroll
        for (int i = 0; i < 128; ++i)
            wreg[i] = wsrc[(size_t)(half * 128 + i) * H3 + col];
    }

    float h_own = 0.f;                         // fp32 carried h (roles 0/2)

    for (int t = 0; t < SS; ++t) {
        const int row = t * BB + b;
        float xr = 0.f, xz = 0.f, xn = 0.f;
        if (role == 0 && tid < 32) {           // prefetch x-preacts (indep.)
            const int j = p * 32 + tid;
            xr = (float)xW0[(size_t)row * H3 + j];
            xz = (float)xW0[(size_t)row * H3 + HH + j];
            xn = (float)xW0[(size_t)row * H3 + 2 * HH + j];
        }

        // ---- poll + stage dot-operand vector into LDS ----
        if (role == 0) {
            if (t > 0) {
                if (tid < 64) {
                    const int* fp = flag0 + b * GPB + (tid & 15);
                    for (;;) {
                        int v = __hip_atomic_load(fp, __ATOMIC_RELAXED,
                                                  __HIP_MEMORY_SCOPE_AGENT);
                        if (__all(v >= t)) break;
                        __builtin_amdgcn_s_sleep(1);
                    }
                }
                __syncthreads();
                const unsigned int* src = hbuf0 + (size_t)((t - 1) * BB + b) * 256;
                hls[tid] = __hip_atomic_load(src + tid, __ATOMIC_RELAXED,
                                             __HIP_MEMORY_SCOPE_AGENT);
            } else hls[tid] = 0u;
        } else if (role == 1) {
            if (tid < 64) {
                const int* fp = flag0 + b * GPB + (tid & 15);
                for (;;) {
                    int v = __hip_atomic_load(fp, __ATOMIC_RELAXED,
                                              __HIP_MEMORY_SCOPE_AGENT);
                    if (__all(v >= t + 1)) break;
                    __builtin_amdgcn_s_sleep(1);
                }
            }
            __syncthreads();
            const unsigned int* src = hbuf0 + (size_t)(t * BB + b) * 256;
            hls[tid] = __hip_atomic_load(src + tid, __ATOMIC_RELAXED,
                                         __HIP_MEMORY_SCOPE_AGENT);
        } else {
            if (tid < 64) {
                const int* fp; int tgt;
                if (tid < 16)       { fp = flag1  + b * GPB + tid; tgt = t; }
                else if (tid == 16) { fp = flag_ih + b * GPB + p;  tgt = t + 1; }
                else                { fp = flag1  + b * GPB;       tgt = INT_MIN; }
                for (;;) {
                    int v = __hip_atomic_load(fp, __ATOMIC_RELAXED,
                                              __HIP_MEMORY_SCOPE_AGENT);
                    if (__all(v >= tgt)) break;
                    __builtin_amdgcn_s_sleep(1);
                }
            }
            __syncthreads();
            if (t > 0) {
                const unsigned int* src = hbuf1 + (size_t)((t - 1) * BB + b) * 256;
                hls[tid] = __hip_atomic_load(src + tid, __ATOMIC_RELAXED,
                                             __HIP_MEMORY_SCOPE_AGENT);
            } else hls[tid] = 0u;
            if (tid < 32) {                    // x-preacts from ih stage
                const unsigned int* xb = xw1buf + (size_t)((t * BB + b) * GPB + p) * 48;
                unsigned int d0 = __hip_atomic_load(xb + (tid >> 1),
                                    __ATOMIC_RELAXED, __HIP_MEMORY_SCOPE_AGENT);
                unsigned int d1 = __hip_atomic_load(xb + 16 + (tid >> 1),
                                    __ATOMIC_RELAXED, __HIP_MEMORY_SCOPE_AGENT);
                unsigned int d2 = __hip_atomic_load(xb + 32 + (tid >> 1),
                                    __ATOMIC_RELAXED, __HIP_MEMORY_SCOPE_AGENT);
                xr = (float)u2h2(d0)[tid & 1];
                xz = (float)u2h2(d1)[tid & 1];
                xn = (float)u2h2(d2)[tid & 1];
            }
        }
        __syncthreads();

        // ---- 96 dots of length 512: register weights x broadcast-LDS v ----
        if (tid < 192) {
            float a0 = 0.f, a1 = 0.f, a2 = 0.f, a3 = 0.f;
            const uint4* hp = (const uint4*)&hls[half * 128];
#pragma unroll
            for (int i = 0; i < 32; ++i) {
                const uint4 hv = hp[i];
                a0 = __builtin_amdgcn_fdot2(u2h2(wreg[4 * i + 0]), u2h2(hv.x), a0, false);
                a1 = __builtin_amdgcn_fdot2(u2h2(wreg[4 * i + 1]), u2h2(hv.y), a1, false);
                a2 = __builtin_amdgcn_fdot2(u2h2(wreg[4 * i + 2]), u2h2(hv.z), a2, false);
                a3 = __builtin_amdgcn_fdot2(u2h2(wreg[4 * i + 3]), u2h2(hv.w), a3, false);
            }
            float acc = (a0 + a1) + (a2 + a3);
            acc += __shfl_xor(acc, 1, 64);     // combine k-halves
            if (half == 0) dots[r] = acc + bias;
        }
        __syncthreads();

        // ---- role epilogues ----
        if (role == 1) {
            // wave-0-only pack & publish the 96 xW1 values (48 dwords)
            if (tid < 48) {
                const unsigned int pk = (unsigned int)f2h(dots[2 * tid])
                                      | ((unsigned int)f2h(dots[2 * tid + 1]) << 16);
                __hip_atomic_store(
                    xw1buf + (size_t)((t * BB + b) * GPB + p) * 48 + tid,
                    pk, __ATOMIC_RELAXED, __HIP_MEMORY_SCOPE_AGENT);
            }
            if (tid == 0) {
                __builtin_amdgcn_s_waitcnt(0);
                __hip_atomic_store(flag_ih + b * GPB + p, t + 1,
                                   __ATOMIC_RELAXED, __HIP_MEMORY_SCOPE_AGENT);
            }
        } else {
            if (tid < 32) {
                const float ar = dots[tid];
                const float az = dots[32 + tid];
                const float an = dots[64 + tid];
                const float rg = 1.f / (1.f + __expf(-(xr + ar)));
                const float zg = 1.f / (1.f + __expf(-(xz + az)));
                const float nn = xn + rg * an;
                const float e  = __expf(-2.f * nn);
                const float ng = (1.f - e) / (1.f + e);      // tanh
                const float hnew = (1.f - zg) * ng + zg * h_own;
                h_own = hnew;
                if (role == 2)
                    ys1[(size_t)row * HH + p * 32 + tid] = (_Float16)hnew;
                const float other = __shfl_xor(hnew, 1, 64);
                if ((tid & 1) == 0) {
                    const unsigned int pk = (unsigned int)f2h(hnew)
                                          | ((unsigned int)f2h(other) << 16);
                    unsigned int* dst = (role == 0 ? hbuf0 : hbuf1)
                                      + (size_t)(t * BB + b) * 256 + p * 16 + (tid >> 1);
                    __hip_atomic_store(dst, pk, __ATOMIC_RELAXED,
                                       __HIP_MEMORY_SCOPE_AGENT);
                }
            }
            if (tid == 0) {
                __builtin_amdgcn_s_waitcnt(0);
                int* fl = (role == 0 ? flag0 : flag1) + b * GPB + p;
                __hip_atomic_store(fl, t + 1, __ATOMIC_RELAXED,
                                   __HIP_MEMORY_SCOPE_AGENT);
            }
        }
        __syncthreads();   // protect hls/dots reuse next step
    }
}

// ---------------------------------------------------------------------------
// 4) Fused LayerNorm + classification head. One WG per output row.
// ---------------------------------------------------------------------------
__global__ __launch_bounds__(256) void ln_head_kernel(
        const float* __restrict__ X,      // (S*B, D), row = s*16+b
        const float* __restrict__ gamma,
        const float* __restrict__ beta,
        const float* __restrict__ Wh,     // (3, 1024)
        const float* __restrict__ bh,     // (3)
        float*       __restrict__ out)    // (B*S, 3)
{
    __shared__ float red[12];
    const int r  = blockIdx.x;            // b*64 + s
    const int bI = r >> 6;
    const int s  = r & 63;
    const float* x = X + (size_t)(s * BB + bI) * DD;
    const int tid = threadIdx.x;
    const float4 v = *(const float4*)(x + tid * 4);
    float sum = v.x + v.y + v.z + v.w;
    float ss  = v.x * v.x + v.y * v.y + v.z * v.z + v.w * v.w;
#pragma unroll
    for (int o = 32; o > 0; o >>= 1) {
        sum += __shfl_down(sum, o, 64);
        ss  += __shfl_down(ss,  o, 64);
    }
    const int lane = tid & 63, w = tid >> 6;
    if (lane == 0) { red[w] = sum; red[4 + w] = ss; }
    __syncthreads();
    const float tsum = red[0] + red[1] + red[2] + red[3];
    const float tss  = red[4] + red[5] + red[6] + red[7];
    const float mu  = tsum * (1.f / (float)DD);
    const float var = tss * (1.f / (float)DD) - mu * mu;
    const float inv = rsqrtf(var + 1e-5f);
    const float4 g  = *(const float4*)(gamma + tid * 4);
    const float4 be = *(const float4*)(beta + tid * 4);
    float y0 = (v.x - mu) * inv * g.x + be.x;
    float y1 = (v.y - mu) * inv * g.y + be.y;
    float y2 = (v.z - mu) * inv * g.z + be.z;
    float y3 = (v.w - mu) * inv * g.w + be.w;
    const float4 w0 = *(const float4*)(Wh + 0 * DD + tid * 4);
    const float4 w1 = *(const float4*)(Wh + 1 * DD + tid * 4);
    const float4 w2 = *(const float4*)(Wh + 2 * DD + tid * 4);
    float p0 = y0 * w0.x + y1 * w0.y + y2 * w0.z + y3 * w0.w;
    float p1 = y0 * w1.x + y1 * w1.y + y2 * w1.z + y3 * w1.w;
    float p2 = y0 * w2.x + y1 * w2.y + y2 * w2.z + y3 * w2.w;
#pragma unroll
    for (int o = 32; o > 0; o >>= 1) {
        p0 += __shfl_down(p0, o, 64);
        p1 += __shfl_down(p1, o, 64);
        p2 += __shfl_down(p2, o, 64);
    }
    __syncthreads();
    if (lane == 0) { red[w] = p0; red[4 + w] = p1; red[8 + w] = p2; }
    __syncthreads();
    if (tid == 0) {
        out[(size_t)r * NCLS + 0] = red[0] + red[1] + red[2]  + red[3]  + bh[0];
        out[(size_t)r * NCLS + 1] = red[4] + red[5] + red[6]  + red[7]  + bh[1];
        out[(size_t)r * NCLS + 2] = red[8] + red[9] + red[10] + red[11] + bh[2];
    }
}

// ---------------------------------------------------------------------------
extern "C" void kernel_launch(void* const* d_in, const int* in_sizes, int n_in,
                              void* d_out, int out_size, void* d_ws, size_t ws_size,
                              hipStream_t stream) {
    const float* hs      = (const float*)d_in[0];
    const float* W_down  = (const float*)d_in[1];
    const float* b_down  = (const float*)d_in[2];
    const float* W_ih0   = (const float*)d_in[3];
    const float* W_hh0   = (const float*)d_in[4];
    const float* b_ih0   = (const float*)d_in[5];
    const float* b_hh0   = (const float*)d_in[6];
    const float* W_ih1   = (const float*)d_in[7];
    const float* W_hh1   = (const float*)d_in[8];
    const float* b_ih1   = (const float*)d_in[9];
    const float* b_hh1   = (const float*)d_in[10];
    const float* W_lin1  = (const float*)d_in[11];
    const float* b_lin1  = (const float*)d_in[12];
    const float* gamma   = (const float*)d_in[13];
    const float* beta    = (const float*)d_in[14];
    const float* W_head  = (const float*)d_in[15];
    const float* b_head  = (const float*)d_in[16];
    const int*   gidx    = (const int*)d_in[17];
    float* out = (float*)d_out;

    char* ws = (char*)d_ws;
    const size_t KB = (size_t)1 << 10;
    const size_t MB = (size_t)1 << 20;
    // Live ranges: pooledh/xd_h/xW0_h dead by the time their space is reused.
    float*        pooled  = (float*)(ws);                      //  0..4  MB (live till lin1)
    _Float16*     pooledh = (_Float16*)(ws + 4 * MB);          //  4..6  (dead after down)
    _Float16*     xd_h    = (_Float16*)(ws + 6 * MB);          //  6..7  (dead after ih0)
    _Float16*     xW0_h   = (_Float16*)(ws + 7 * MB);          //  7..10 (dead after gru)
    _Float16*     ys1_h   = (_Float16*)(ws + 10 * MB);         // 10..11
    unsigned int* wp0     = (unsigned int*)(ws + 11 * MB);     // 11..12.5
    unsigned int* wp1     = (unsigned int*)(ws + 11 * MB + 1536 * KB);
    unsigned int* wpih1   = (unsigned int*)(ws + 14 * MB);     // 14..15.5
    _Float16*     wdown_h = (_Float16*)(ws + 15 * MB + 512 * KB); // 15.5..16.5
    _Float16*     wih0_h  = (_Float16*)(ws + 16 * MB + 512 * KB); // 16.5..18
    _Float16*     wlin1_h = (_Float16*)(ws + 18 * MB);         // 18..19
    unsigned int* xw1buf  = (unsigned int*)(ws + 19 * MB);     // 19..22 (3 MB)
    int*          flags   = (int*)(ws + 22 * MB);              // 768 ints
    // gru-only buffers overlap pooledh (dead before gru starts)
    unsigned int* hbuf0   = (unsigned int*)(ws + 4 * MB);      //  4..5
    unsigned int* hbuf1   = (unsigned int*)(ws + 5 * MB);      //  5..6
    // lin1 output overlaps pooledh/xd_h/xW0_h head (all dead by lin1)
    float*        xln     = (float*)(ws + 4 * MB);             //  4..8

    int* flag0  = flags;
    int* flagih = flags + 256;
    int* flag1  = flags + 512;

    // 1) pooling + all weight prep + flag zero (one launch)
    prep_pool_kernel<<<4225, 256, 0, stream>>>(
        hs, gidx, pooled, pooledh,
        W_hh0, W_hh1, W_ih1, wp0, wp1, wpih1,
        W_down, W_ih0, W_lin1, wdown_h, wih0_h, wlin1_h, flags);

    // 2) down-projection: xd = pooled @ W_down^T + b_down  (f16 out)
    gemm_mfma_kernel<DD, true><<<dim3(HH / 64, (SS * BB) / 64), 256, 0, stream>>>(
        pooledh, wdown_h, b_down, nullptr, xd_h, HH);

    // 3) layer-0 input projection: xW0 = xd @ W_ih0^T + b_ih0  (f16 out)
    gemm_mfma_kernel<HH, true><<<dim3(H3 / 64, (SS * BB) / 64), 256, 0, stream>>>(
        xd_h, wih0_h, b_ih0, nullptr, xW0_h, H3);

    // 4) fused two-layer pipelined GRU (includes layer-1 input projection)
    gru_fused_kernel<<<3 * BB * GPB, 256, 0, stream>>>(
        xW0_h, wp0, b_hh0, wpih1, b_ih1, wp1, b_hh1,
        ys1_h, hbuf0, hbuf1, xw1buf, flag0, flagih, flag1);

    // 5) up-projection + residual: xln = pooled + ys1 @ W_lin1^T + b_lin1
    gemm_mfma_kernel<HH, false><<<dim3(DD / 64, (SS * BB) / 64), 256, 0, stream>>>(
        ys1_h, wlin1_h, b_lin1, pooled, xln, DD);

    // 6) LayerNorm + head
    ln_head_kernel<<<BB * SS, 256, 0, stream>>>(xln, gamma, beta, W_head, b_head, out);
}